// Round 7
// baseline (18082.448 us; speedup 1.0000x reference)
//
#include <hip/hip_runtime.h>

#define B_ 128
#define T_ 2048
#define D_ 128
#define H_ 512
#define L_ 10
#define NSTR 4    // streams (batch groups) per WG: {p, p+2, p+4, p+6}
#define NPR 2     // parity classes
#define NS 16     // gate-slice WGs per group
#define GB 16     // batches per group (MFMA N)
#define HS 32     // hidden units per slice
#define NKK 20    // K-steps of 32 (16 h-steps + 4 x-steps)

typedef __attribute__((ext_vector_type(8))) short short8;
typedef __attribute__((ext_vector_type(4))) float f32x4;
typedef unsigned long long u64;

__device__ __forceinline__ unsigned short f2bf(float f) {
    union { float f; unsigned u; } v; v.f = f;
    unsigned r = v.u + 0x7fffu + ((v.u >> 16) & 1u);
    return (unsigned short)(r >> 16);
}
__device__ __forceinline__ float fast_sig(float x) {
    return 1.f / (1.f + __expf(-x));
}
__device__ __forceinline__ float fast_tanh(float x) {
    return 1.f - 2.f / (__expf(2.f * x) + 1.f);
}
__device__ __forceinline__ u64 h_ld(const u64* p) {
    return __hip_atomic_load(p, __ATOMIC_RELAXED, __HIP_MEMORY_SCOPE_AGENT);
}
__device__ __forceinline__ void h_st(u64* p, u64 v) {
    __hip_atomic_store(p, v, __ATOMIC_RELAXED, __HIP_MEMORY_SCOPE_AGENT);
}
__device__ __forceinline__ void f_st(unsigned* p, unsigned v) {
    __hip_atomic_store(p, v, __ATOMIC_RELAXED, __HIP_MEMORY_SCOPE_AGENT);
}
__device__ __forceinline__ short8 packx(const float4 a, const float4 b) {
    short8 v;
    v[0]=(short)f2bf(a.x); v[1]=(short)f2bf(a.y);
    v[2]=(short)f2bf(a.z); v[3]=(short)f2bf(a.w);
    v[4]=(short)f2bf(b.x); v[5]=(short)f2bf(b.y);
    v[6]=(short)f2bf(b.z); v[7]=(short)f2bf(b.w);
    return v;
}

// Persistent quad-stream LSTM, JOINT-WAIT schedule. 32 WGs = 16 slices x 2
// parities; WG (p,s) runs groups {p,p+2,p+4,p+6} on shared slice weights.
// Per iteration (= 4 LSTM steps, one per group):
//   [4x: MFMA_j + cell_j + h-store_j]  -> one vmcnt(0) drain -> publish 4
//   flags -> issue x(t+1) loads -> syncthreads -> JOINT poll of all 4
//   groups' 128 wave-flags -> reload h(t+1) x4 -> restage LDS -> sync.
// The 4 handoff WAITS are merged into one spin (R6's error: polls were
// serialized before each compute). All cross-WG ops are the R1-verified
// agent-scope relaxed atomics.
__global__ __launch_bounds__(512, 2) void lstm_kernel(
    const float* __restrict__ x, const float* __restrict__ W_ih,
    const float* __restrict__ W_hh, const float* __restrict__ bias,
    u64* h_buf,               // [2][16384] u64 = [2][128][512] bf16
    unsigned int* flags,      // [8][128] per-(group, slice*8+wave) counters
    float* __restrict__ hfin) // [128][512] fp32
{
    const int p    = blockIdx.x & (NPR - 1);
    const int s    = blockIdx.x >> 1;
    const int tid  = threadIdx.x;
    const int lane = tid & 63;
    const int w    = tid >> 6;     // wave 0..7
    const int quad = lane >> 4;    // 0..3
    const int col  = lane & 15;    // MFMA N index (batch within group)

    __shared__ __align__(16) short Bst[NSTR][NKK * 64 * 8];   // 81920 B

    // ---- one-time: gate-interleaved weight A-fragments (slice-only dep) ----
    short8 wfrag[NKK];
    {
        const int m = col;
        const int r = (m & 3) * 512 + s * HS + w * 4 + (m >> 2);
        #pragma unroll
        for (int kk = 0; kk < NKK; ++kk) {
            const int k0 = kk * 32 + quad * 8;
            short8 v;
            #pragma unroll
            for (int j = 0; j < 8; ++j) {
                const int k = k0 + j;
                const float f = (k < 512) ? W_hh[r * 512 + k]
                                          : W_ih[r * 128 + (k - 512)];
                v[j] = (short)f2bf(f);
            }
            wfrag[kk] = v;
        }
    }

    const int hu_g = s * HS + w * 4 + quad;
    const float bi  = bias[0 * 512 + hu_g];
    const float bfv = bias[1 * 512 + hu_g];
    const float bg  = bias[2 * 512 + hu_g];
    const float bo  = bias[3 * 512 + hu_g];
    float cst[NSTR] = {0.f, 0.f, 0.f, 0.f};

    // x staging (waves 0..3); stream j adds j*XSTR
    const float* xb = nullptr;
    int xc = 0;
    if (tid < 256) {
        const int kk = tid >> 6, ln = tid & 63;
        const int n  = ln & 15;
        const int k0 = kk * 32 + (ln >> 4) * 8;
        xb = x + (size_t)(p * GB + n) * T_ * D_ + k0;
        xc = (16 + kk) * 64 + ln;
    }
    const size_t XSTR = (size_t)2 * GB * T_ * D_;   // +2 groups in floats

    // h chunk addressing (u64 units); stream j adds j*GSTR
    const int hc0 = tid, hc1 = tid + 512;
    auto hoff = [](int c, int g) -> size_t {
        const int ln = c & 63, kk = c >> 6;
        return (size_t)(g * GB + (ln & 15)) * 128 + (size_t)(kk * 8 + (ln >> 4) * 2);
    };
    u64* hp0 = h_buf + hoff(hc0, p);
    u64* hp1 = h_buf + hoff(hc1, p);
    u64* hd  = h_buf + (size_t)(p * GB + col) * 128 + s * 8 + w;
    const size_t GSTR = (size_t)2 * GB * 128;        // 4096 u64 per 2 groups
    unsigned*       pf = flags + p * 128 + s * 8 + w;   // publish; + j*256
    const unsigned* q0 = flags + p * 128 + lane;        // poll;    + j*256, +64

    // ---- prologue: h(0)=0 and x(0) into all 4 stream LDS buffers ----
    {
        short8 z = {0, 0, 0, 0, 0, 0, 0, 0};
        #pragma unroll
        for (int j = 0; j < NSTR; ++j) {
            *(short8*)&Bst[j][hc0 * 8] = z;
            *(short8*)&Bst[j][hc1 * 8] = z;
        }
        if (tid < 256) {
            #pragma unroll
            for (int j = 0; j < NSTR; ++j) {
                const float4* pp = (const float4*)(xb + (size_t)j * XSTR);
                *(short8*)&Bst[j][xc * 8] = packx(pp[0], pp[1]);
            }
        }
    }
    __syncthreads();

    int budget = 1 << 24;   // anti-hang guard: degrade, never hang

    for (int t = 0; t < T_; ++t) {
        const unsigned tt = (unsigned)(t + 1);
        const size_t   pn = (size_t)(tt & 1) * 16384;

        // ---- 4 compute phases, back-to-back (no polls in between) ----
        #pragma unroll
        for (int j = 0; j < NSTR; ++j) {
            f32x4 acc0 = {0,0,0,0}, acc1 = {0,0,0,0};
            #pragma unroll
            for (int kk = 0; kk < NKK; kk += 2) {
                const short8 b0 = *(const short8*)&Bst[j][(kk * 64 + lane) * 8];
                const short8 b1 = *(const short8*)&Bst[j][((kk + 1) * 64 + lane) * 8];
                acc0 = __builtin_amdgcn_mfma_f32_16x16x32_bf16(wfrag[kk], b0, acc0, 0, 0, 0);
                acc1 = __builtin_amdgcn_mfma_f32_16x16x32_bf16(wfrag[kk + 1], b1, acc1, 0, 0, 0);
            }
            const float gi = acc0[0] + acc1[0] + bi;
            const float gf = acc0[1] + acc1[1] + bfv;
            const float gg = acc0[2] + acc1[2] + bg;
            const float go = acc0[3] + acc1[3] + bo;
            cst[j] = fast_sig(gf) * cst[j] + fast_sig(gi) * fast_tanh(gg);
            const float h = fast_sig(go) * fast_tanh(cst[j]);
            if (t < T_ - 1) {
                const float h1 = __shfl_down(h, 16, 64);
                const float h2 = __shfl_down(h, 32, 64);
                const float h3 = __shfl_down(h, 48, 64);
                if (quad == 0)
                    h_st(hd + (size_t)j * GSTR + pn,
                         (u64)f2bf(h)          | ((u64)f2bf(h1) << 16)
                       | ((u64)f2bf(h2) << 32) | ((u64)f2bf(h3) << 48));
            } else {
                hfin[(size_t)((p + 2 * j) * GB + col) * H_ + hu_g] = h;
            }
        }
        if (t == T_ - 1) break;   // hfin flushed at kernel end; nobody polls T

        // ---- single drain, then publish all 4 flags ----
        asm volatile("s_waitcnt vmcnt(0)" ::: "memory");
        if (lane == 0) {
            #pragma unroll
            for (int j = 0; j < NSTR; ++j) f_st(pf + j * 256, tt);
        }

        // ---- issue x(t+1) loads: fly under sync + joint poll ----
        float4 xv[NSTR][2];
        if (tid < 256) {
            #pragma unroll
            for (int j = 0; j < NSTR; ++j) {
                const float4* pp =
                    (const float4*)(xb + (size_t)j * XSTR + (size_t)(t + 1) * D_);
                xv[j][0] = pp[0]; xv[j][1] = pp[1];
            }
        }

        __syncthreads();   // all compute done -> LDS safe to restage after poll

        // ---- JOINT poll: all 4 groups' 128 wave-flags, 8 per lane ----
        for (;;) {
            unsigned mn = 0xffffffffu;
            #pragma unroll
            for (int j = 0; j < NSTR; ++j) {
                const unsigned a = __hip_atomic_load(q0 + j * 256,
                        __ATOMIC_RELAXED, __HIP_MEMORY_SCOPE_AGENT);
                const unsigned b = __hip_atomic_load(q0 + j * 256 + 64,
                        __ATOMIC_RELAXED, __HIP_MEMORY_SCOPE_AGENT);
                mn = mn < a ? mn : a;
                mn = mn < b ? mn : b;
            }
            if (mn >= tt || --budget <= 0) break;
        }
        __asm__ __volatile__("" ::: "memory");

        // ---- reload h(t+1) for all streams (parallel issue), restage LDS ----
        u64 ra[NSTR][4];
        #pragma unroll
        for (int j = 0; j < NSTR; ++j) {
            ra[j][0] = h_ld(hp0 + (size_t)j * GSTR + pn);
            ra[j][1] = h_ld(hp0 + (size_t)j * GSTR + pn + 1);
            ra[j][2] = h_ld(hp1 + (size_t)j * GSTR + pn);
            ra[j][3] = h_ld(hp1 + (size_t)j * GSTR + pn + 1);
        }
        #pragma unroll
        for (int j = 0; j < NSTR; ++j) {
            union { u64 q[2]; short8 v; } u0, u1;
            u0.q[0] = ra[j][0]; u0.q[1] = ra[j][1];
            u1.q[0] = ra[j][2]; u1.q[1] = ra[j][3];
            *(short8*)&Bst[j][hc0 * 8] = u0.v;
            *(short8*)&Bst[j][hc1 * 8] = u1.v;
        }
        if (tid < 256) {
            #pragma unroll
            for (int j = 0; j < NSTR; ++j)
                *(short8*)&Bst[j][xc * 8] = packx(xv[j][0], xv[j][1]);
        }
        __syncthreads();
    }
}

// Head: logits = h_final @ W_out^T, softmax. One wave per batch row.
__global__ void head_kernel(const float* __restrict__ hfin,
                            const float* __restrict__ W_out,
                            float* __restrict__ out)
{
    const int bidx = blockIdx.x;
    const int l    = threadIdx.x;      // 0..63
    float hv[8];
    #pragma unroll
    for (int j = 0; j < 8; ++j) hv[j] = hfin[bidx * 512 + j * 64 + l];
    __shared__ float logits[L_];
    for (int o = 0; o < L_; ++o) {
        float p = 0.f;
        #pragma unroll
        for (int j = 0; j < 8; ++j) p += hv[j] * W_out[o * 512 + j * 64 + l];
        #pragma unroll
        for (int off = 32; off; off >>= 1) p += __shfl_down(p, off, 64);
        if (l == 0) logits[o] = p;
    }
    __syncthreads();
    if (l == 0) {
        float mx = logits[0];
        for (int o = 1; o < L_; ++o) mx = fmaxf(mx, logits[o]);
        float e[L_], sum = 0.f;
        for (int o = 0; o < L_; ++o) { e[o] = __expf(logits[o] - mx); sum += e[o]; }
        const float inv = 1.f / sum;
        for (int o = 0; o < L_; ++o) out[bidx * L_ + o] = e[o] * inv;
    }
}

extern "C" void kernel_launch(void* const* d_in, const int* in_sizes, int n_in,
                              void* d_out, int out_size, void* d_ws, size_t ws_size,
                              hipStream_t stream) {
    const float* x     = (const float*)d_in[0];
    const float* W_ih  = (const float*)d_in[1];
    const float* W_hh  = (const float*)d_in[2];
    const float* bias  = (const float*)d_in[3];
    const float* W_out = (const float*)d_in[4];
    float* out = (float*)d_out;

    // ws: h_buf [2][128][512] bf16 (262144) | flags [8][128] u32 (4096) |
    //     hfin [128][512] f32 (262144)
    char* ws = (char*)d_ws;
    u64*          h_buf = (u64*)ws;
    unsigned int* flags = (unsigned int*)(ws + 262144);
    float*        hfin  = (float*)(ws + 262144 + 4096);

    hipMemsetAsync(ws, 0, 262144 + 4096, stream);

    void* args[] = { (void*)&x, (void*)&W_ih, (void*)&W_hh, (void*)&bias,
                     (void*)&h_buf, (void*)&flags, (void*)&hfin };
    hipLaunchCooperativeKernel((void*)lstm_kernel, dim3(NPR * NS), dim3(512),
                               args, 0, stream);
    head_kernel<<<dim3(B_), dim3(64), 0, stream>>>(hfin, W_out, out);
}

// Round 11
// 9006.481 us; speedup vs baseline: 2.0077x; 2.0077x over previous
//
#include <hip/hip_runtime.h>

#define B_ 128
#define T_ 2048
#define D_ 128
#define H_ 512
#define L_ 10
#define NG 8      // batch groups
#define GB 16     // batches per group (MFMA N)
#define NS 16     // gate-slice workgroups per group
#define HS 32     // hidden units per slice
#define NKK 20    // K-steps of 32 (16 h-steps + 4 x-steps)

typedef __attribute__((ext_vector_type(8))) short short8;
typedef __attribute__((ext_vector_type(4))) float f32x4;
typedef unsigned long long u64;

__device__ __forceinline__ unsigned short f2bf(float f) {
    union { float f; unsigned u; } v; v.f = f;
    unsigned r = v.u + 0x7fffu + ((v.u >> 16) & 1u);
    return (unsigned short)(r >> 16);
}
__device__ __forceinline__ float fast_sig(float x) {
    return 1.f / (1.f + __expf(-x));
}
__device__ __forceinline__ float fast_tanh(float x) {
    return 1.f - 2.f / (__expf(2.f * x) + 1.f);
}
__device__ __forceinline__ u64 h_ld(const u64* p) {
    return __hip_atomic_load(p, __ATOMIC_RELAXED, __HIP_MEMORY_SCOPE_AGENT);
}
__device__ __forceinline__ void h_st(u64* p, u64 v) {
    __hip_atomic_store(p, v, __ATOMIC_RELAXED, __HIP_MEMORY_SCOPE_AGENT);
}

// Persistent LSTM, SELF-VALIDATING h exchange. Structure = R1 (best
// measured: 128 WGs = 8 groups x 16 slices, one exchange per step), but the
// flag protocol is replaced: each h bf16-PAIR is stored as one u64 unit
// (seq<<32 | 2xbf16), relying on 64-bit single-copy atomicity of relaxed
// agent-scope atomics. Producer: store units at cell end -- no drain, no
// flag, no publish RT. Consumer: spin-load its own 8 units until all carry
// seq == t -- poll and reload are the SAME load (1 IF$ round trip instead
// of R1's 3). WAR safety: slot parity reuse (seq t+1 -> t+3) requires every
// consumer's t+1 staging read to have completed (producer of t+3 verified
// h(t+2), which needs this WG's t+2 stores, which follow its t+1 read).
__global__ __launch_bounds__(512, 2) void lstm_kernel(
    const float* __restrict__ x, const float* __restrict__ W_ih,
    const float* __restrict__ W_hh, const float* __restrict__ bias,
    u64* h_units,             // [2][8][16][256] u64: (seq<<32 | bf16 pair)
    float* __restrict__ hfin) // [128][512] fp32
{
    const int g    = blockIdx.x & 7;
    const int s    = blockIdx.x >> 3;
    const int tid  = threadIdx.x;
    const int lane = tid & 63;
    const int w    = tid >> 6;     // wave 0..7
    const int quad = lane >> 4;    // 0..3
    const int col  = lane & 15;    // MFMA N index (batch within group)

    __shared__ __align__(16) short Bstage[NKK * 64 * 8];   // 20480 B

    // ---- one-time: gate-interleaved weight A-fragments (bf16) ----
    // tile row m -> weight row (m&3)*512 + s*32 + w*4 + (m>>2); K=[h(512)|x(128)]
    short8 wfrag[NKK];
    {
        const int m = col;
        const int r = (m & 3) * 512 + s * HS + w * 4 + (m >> 2);
        #pragma unroll
        for (int kk = 0; kk < NKK; ++kk) {
            const int k0 = kk * 32 + quad * 8;
            short8 v;
            #pragma unroll
            for (int j = 0; j < 8; ++j) {
                const int k = k0 + j;
                const float f = (k < 512) ? W_hh[r * 512 + k]
                                          : W_ih[r * 128 + (k - 512)];
                v[j] = (short)f2bf(f);
            }
            wfrag[kk] = v;
        }
    }

    // ---- per-lane output element: C/D row quad -> gate rr in acc[rr] ----
    const int hu_g = s * HS + w * 4 + quad;
    const float bi  = bias[0 * 512 + hu_g];
    const float bfv = bias[1 * 512 + hu_g];
    const float bg  = bias[2 * 512 + hu_g];
    const float bo  = bias[3 * 512 + hu_g];
    float c_val = 0.f;

    // x staging addresses (waves 0..3 only) -- identical to R1
    const float* xbase = nullptr;
    int xc = 0;
    if (tid < 256) {
        const int kk = tid >> 6;              // 0..3
        const int ln = tid & 63;
        const int n  = ln & 15;
        const int k0 = kk * 32 + (ln >> 4) * 8;
        xbase = x + (size_t)(g * GB + n) * T_ * D_ + k0;
        xc = (16 + kk) * 64 + ln;
    }

    // h unit addressing: units laid out [slot][group 8][batch 16][kpair 256].
    // Consumer thread stages chunks hc0=tid, hc1=tid+512: batch n=tid&15,
    // kpair base kp0 = (tid>>6)*16 + ((tid&63)>>4)*4 (4 consecutive units),
    // hc1 at kp0+128.
    const int n_c  = tid & 15;
    const int kp0  = (tid >> 6) * 16 + ((tid & 63) >> 4) * 4;
    const u64* hq_base = h_units + (size_t)(g * GB + n_c) * 256;
    // Producer: quads 0,2 store pair (h[hu], h[hu+1]) at kpair s*16+w*2+(quad>>1)
    u64* hd = h_units + (size_t)(g * GB + col) * 256 + s * 16 + w * 2 + (quad >> 1);

    int budget = 1 << 22;   // anti-hang guard: degrade, never hang

    for (int t = 0; t < T_; ++t) {
        // ---- stage x fragments (issued first: HBM latency flies under spin) ----
        if (tid < 256) {
            const float4* p = (const float4*)(xbase + (size_t)t * D_);
            const float4 xa = p[0], xb = p[1];
            short8 v;
            v[0] = (short)f2bf(xa.x); v[1] = (short)f2bf(xa.y);
            v[2] = (short)f2bf(xa.z); v[3] = (short)f2bf(xa.w);
            v[4] = (short)f2bf(xb.x); v[5] = (short)f2bf(xb.y);
            v[6] = (short)f2bf(xb.z); v[7] = (short)f2bf(xb.w);
            *(short8*)&Bstage[xc * 8] = v;
        }

        // ---- self-validating h load: spin until all 8 units carry seq==t ----
        if (t > 0) {
            const unsigned expseq = (unsigned)t;
            const u64* hq = hq_base + (size_t)(t & 1) * 32768;
            u64 u0, u1, u2, u3, u4, u5, u6, u7;
            for (;;) {
                u0 = h_ld(hq + kp0 + 0);       u1 = h_ld(hq + kp0 + 1);
                u2 = h_ld(hq + kp0 + 2);       u3 = h_ld(hq + kp0 + 3);
                u4 = h_ld(hq + kp0 + 128);     u5 = h_ld(hq + kp0 + 129);
                u6 = h_ld(hq + kp0 + 130);     u7 = h_ld(hq + kp0 + 131);
                bool ok = ((unsigned)(u0 >> 32) == expseq) &
                          ((unsigned)(u1 >> 32) == expseq) &
                          ((unsigned)(u2 >> 32) == expseq) &
                          ((unsigned)(u3 >> 32) == expseq) &
                          ((unsigned)(u4 >> 32) == expseq) &
                          ((unsigned)(u5 >> 32) == expseq) &
                          ((unsigned)(u6 >> 32) == expseq) &
                          ((unsigned)(u7 >> 32) == expseq);
                if (ok || --budget <= 0) break;
            }
            union { unsigned d[4]; short8 v; } s0, s1;
            s0.d[0] = (unsigned)u0; s0.d[1] = (unsigned)u1;
            s0.d[2] = (unsigned)u2; s0.d[3] = (unsigned)u3;
            s1.d[0] = (unsigned)u4; s1.d[1] = (unsigned)u5;
            s1.d[2] = (unsigned)u6; s1.d[3] = (unsigned)u7;
            *(short8*)&Bstage[tid * 8]         = s0.v;
            *(short8*)&Bstage[(tid + 512) * 8] = s1.v;
        } else {
            short8 z = {0, 0, 0, 0, 0, 0, 0, 0};
            *(short8*)&Bstage[tid * 8]         = z;
            *(short8*)&Bstage[(tid + 512) * 8] = z;
        }
        __syncthreads();

        // ---- MFMA, K=640, two independent accumulator chains ----
        f32x4 acc0 = {0.f, 0.f, 0.f, 0.f}, acc1 = {0.f, 0.f, 0.f, 0.f};
        #pragma unroll
        for (int kk = 0; kk < NKK; kk += 2) {
            const short8 b0 = *(const short8*)&Bstage[(kk * 64 + lane) * 8];
            const short8 b1 = *(const short8*)&Bstage[((kk + 1) * 64 + lane) * 8];
            acc0 = __builtin_amdgcn_mfma_f32_16x16x32_bf16(wfrag[kk], b0, acc0, 0, 0, 0);
            acc1 = __builtin_amdgcn_mfma_f32_16x16x32_bf16(wfrag[kk + 1], b1, acc1, 0, 0, 0);
        }

        // ---- elementwise cell: fully lane-local (acc[rr] = gate rr) ----
        {
            const float gi = acc0[0] + acc1[0] + bi;
            const float gf = acc0[1] + acc1[1] + bfv;
            const float gg = acc0[2] + acc1[2] + bg;
            const float go = acc0[3] + acc1[3] + bo;
            c_val = fast_sig(gf) * c_val + fast_sig(gi) * fast_tanh(gg);
            const float h = fast_sig(go) * fast_tanh(c_val);
            const float h1 = __shfl_down(h, 16, 64);   // hu+1's value (quads 0,2)
            if (t < T_ - 1) {
                if ((quad & 1) == 0) {
                    const unsigned dat = (unsigned)f2bf(h) |
                                         ((unsigned)f2bf(h1) << 16);
                    const u64 unit = (u64)dat | ((u64)(unsigned)(t + 1) << 32);
                    h_st(hd + (size_t)((t + 1) & 1) * 32768, unit);
                }
            } else {
                hfin[(size_t)(g * GB + col) * H_ + hu_g] = h;
            }
        }
        __syncthreads();   // LDS WAR: all MFMA reads done before next staging
    }
}

// Head: logits = h_final @ W_out^T, softmax. One wave per batch row.
__global__ void head_kernel(const float* __restrict__ hfin,
                            const float* __restrict__ W_out,
                            float* __restrict__ out)
{
    const int bidx = blockIdx.x;
    const int l    = threadIdx.x;      // 0..63
    float hv[8];
    #pragma unroll
    for (int j = 0; j < 8; ++j) hv[j] = hfin[bidx * 512 + j * 64 + l];
    __shared__ float logits[L_];
    for (int o = 0; o < L_; ++o) {
        float p = 0.f;
        #pragma unroll
        for (int j = 0; j < 8; ++j) p += hv[j] * W_out[o * 512 + j * 64 + l];
        #pragma unroll
        for (int off = 32; off; off >>= 1) p += __shfl_down(p, off, 64);
        if (l == 0) logits[o] = p;
    }
    __syncthreads();
    if (l == 0) {
        float mx = logits[0];
        for (int o = 1; o < L_; ++o) mx = fmaxf(mx, logits[o]);
        float e[L_], sum = 0.f;
        for (int o = 0; o < L_; ++o) { e[o] = __expf(logits[o] - mx); sum += e[o]; }
        const float inv = 1.f / sum;
        for (int o = 0; o < L_; ++o) out[bidx * L_ + o] = e[o] * inv;
    }
}

extern "C" void kernel_launch(void* const* d_in, const int* in_sizes, int n_in,
                              void* d_out, int out_size, void* d_ws, size_t ws_size,
                              hipStream_t stream) {
    const float* x     = (const float*)d_in[0];
    const float* W_ih  = (const float*)d_in[1];
    const float* W_hh  = (const float*)d_in[2];
    const float* bias  = (const float*)d_in[3];
    const float* W_out = (const float*)d_in[4];
    float* out = (float*)d_out;

    // ws: h_units [2][8][16][256] u64 (524288 B, memset: seq 0 != any t>=1)
    //   | hfin [128][512] f32 (262144 B)
    char* ws = (char*)d_ws;
    u64*   h_units = (u64*)ws;
    float* hfin    = (float*)(ws + 524288);

    hipMemsetAsync(ws, 0, 524288, stream);

    void* args[] = { (void*)&x, (void*)&W_ih, (void*)&W_hh, (void*)&bias,
                     (void*)&h_units, (void*)&hfin };
    hipLaunchCooperativeKernel((void*)lstm_kernel, dim3(NG * NS), dim3(512),
                               args, 0, stream);
    head_kernel<<<dim3(B_), dim3(64), 0, stream>>>(hfin, W_out, out);
}

// Round 15
// 5780.127 us; speedup vs baseline: 3.1284x; 1.5582x over previous
//
#include <hip/hip_runtime.h>

#define B_ 128
#define T_ 2048
#define D_ 128
#define H_ 512
#define L_ 10
#define NG 8      // batch groups
#define GB 16     // batches per group (MFMA N)
#define NS 16     // gate-slice workgroups per group
#define HS 32     // hidden units per slice
#define NKK 20    // K-steps of 32 (16 h-steps + 4 x-steps)

typedef __attribute__((ext_vector_type(8))) short short8;
typedef __attribute__((ext_vector_type(4))) float f32x4;
typedef unsigned long long u64;

__device__ __forceinline__ unsigned short f2bf(float f) {
    union { float f; unsigned u; } v; v.f = f;
    unsigned r = v.u + 0x7fffu + ((v.u >> 16) & 1u);
    return (unsigned short)(r >> 16);
}
__device__ __forceinline__ float fast_sig(float x) {
    return 1.f / (1.f + __expf(-x));
}
__device__ __forceinline__ float fast_tanh(float x) {
    return 1.f - 2.f / (__expf(2.f * x) + 1.f);
}
__device__ __forceinline__ u64 h_ld(const u64* p) {
    return __hip_atomic_load(p, __ATOMIC_RELAXED, __HIP_MEMORY_SCOPE_AGENT);
}
__device__ __forceinline__ void h_st(u64* p, u64 v) {
    __hip_atomic_store(p, v, __ATOMIC_RELAXED, __HIP_MEMORY_SCOPE_AGENT);
}
__device__ __forceinline__ void f_st(unsigned* p, unsigned v) {
    __hip_atomic_store(p, v, __ATOMIC_RELAXED, __HIP_MEMORY_SCOPE_AGENT);
}

// Persistent LSTM = R1 protocol (best measured: 6098 us; flags + separate h
// data, 128 WGs = 8 groups x 16 slices) with two congestion fixes:
//  (1) POLL STORM: only wave 1 lanes 0-15 poll the 16 group flags, with
//      s_sleep(2) backoff (R1: all 1024 threads spun continuously; R11
//      showed spin traffic reaching HBM).
//  (2) WRITE AMPLIFICATION: cell writes h into a 1 KiB LDS block; wave 0
//      alone streams it out as 64 lanes x 2 consecutive u64 agent stores
//      (full 64B-line coverage per instruction pair; R1 scattered 4-8B
//      stores across 8 instructions/line -> WRITE_SIZE 4x actual).
// Store+publish (wave 0) overlaps next iteration's x-staging (waves 4-7)
// and the poll (wave 1). h layout: [slot][g][s][n 0..15][hu 0..31] bf16.
__global__ __launch_bounds__(512, 2) void lstm_kernel(
    const float* __restrict__ x, const float* __restrict__ W_ih,
    const float* __restrict__ W_hh, const float* __restrict__ bias,
    u64* h_buf,               // [2][8][16][128] u64 = [2][g][s][1KB]
    unsigned int* flags,      // [8][16] monotone step counters
    float* __restrict__ hfin) // [128][512] fp32
{
    const int g    = blockIdx.x & 7;
    const int s    = blockIdx.x >> 3;
    const int tid  = threadIdx.x;
    const int lane = tid & 63;
    const int w    = tid >> 6;     // wave 0..7
    const int quad = lane >> 4;    // 0..3
    const int col  = lane & 15;    // MFMA N index (batch within group)

    __shared__ __align__(16) short Bstage[NKK * 64 * 8];        // 20480 B
    __shared__ __align__(16) unsigned short HLDS[GB * HS];      // 1024 B [n][hu]

    // ---- one-time: gate-interleaved weight A-fragments (bf16) ----
    // tile row m -> weight row (m&3)*512 + s*32 + w*4 + (m>>2); K=[h(512)|x(128)]
    short8 wfrag[NKK];
    {
        const int m = col;
        const int r = (m & 3) * 512 + s * HS + w * 4 + (m >> 2);
        #pragma unroll
        for (int kk = 0; kk < NKK; ++kk) {
            const int k0 = kk * 32 + quad * 8;
            short8 v;
            #pragma unroll
            for (int j = 0; j < 8; ++j) {
                const int k = k0 + j;
                const float f = (k < 512) ? W_hh[r * 512 + k]
                                          : W_ih[r * 128 + (k - 512)];
                v[j] = (short)f2bf(f);
            }
            wfrag[kk] = v;
        }
    }

    // ---- per-lane output element: acc[rr] = gate rr of (hu_g, batch col) ----
    const int hu_l = w * 4 + quad;          // hu within slice, 0..31
    const int hu_g = s * HS + hu_l;
    const float bi  = bias[0 * 512 + hu_g];
    const float bfv = bias[1 * 512 + hu_g];
    const float bg  = bias[2 * 512 + hu_g];
    const float bo  = bias[3 * 512 + hu_g];
    float c_val = 0.f;

    // x staging addresses (waves 4..7)
    const float* xbase = nullptr;
    int xc = 0;
    if (tid >= 256) {
        const int c  = tid - 256;            // 0..255
        const int kk = c >> 6;               // 0..3
        const int ln = c & 63;
        const int n  = ln & 15;
        const int k0 = kk * 32 + (ln >> 4) * 8;
        xbase = x + (size_t)(g * GB + n) * T_ * D_ + k0;
        xc = (16 + kk) * 64 + ln;
    }

    // consumer reload addressing: chunk c -> u64 offset within a slot
    auto chunk_addr = [&](int c) -> size_t {
        const int kk = c >> 6, ln = c & 63;
        const int n  = ln & 15;
        const int k0 = kk * 32 + (ln >> 4) * 8;      // hu global 0..511
        return (size_t)(g * 16 + (k0 >> 5)) * 128 + n * 8 + ((k0 & 31) >> 2);
    };
    const size_t ca0 = chunk_addr(tid);
    const size_t ca1 = chunk_addr(tid + 512);

    // wave-0 condensed store: lane covers bytes lane*16 of this WG's 1KB block
    u64* wdst_base = h_buf + ((size_t)g * 16 + s) * 128 + lane * 2;
    unsigned* fpub = flags + g * 16 + s;

    int budget = 1 << 20;   // anti-hang guard (wave 1): degrade, never hang

    for (int t = 0; t < T_; ++t) {
        // ---- phase 1 (no barrier): x-stage (w4-7) || poll (w1) ----
        if (tid >= 256) {
            const float4* p = (const float4*)(xbase + (size_t)t * D_);
            const float4 xa = p[0], xb = p[1];
            short8 v;
            v[0] = (short)f2bf(xa.x); v[1] = (short)f2bf(xa.y);
            v[2] = (short)f2bf(xa.z); v[3] = (short)f2bf(xa.w);
            v[4] = (short)f2bf(xb.x); v[5] = (short)f2bf(xb.y);
            v[6] = (short)f2bf(xb.z); v[7] = (short)f2bf(xb.w);
            *(short8*)&Bstage[xc * 8] = v;
        } else if (w == 1 && t > 0 && lane < 16) {
            const unsigned* fp = flags + g * 16 + lane;
            while (__hip_atomic_load(fp, __ATOMIC_RELAXED,
                                     __HIP_MEMORY_SCOPE_AGENT) < (unsigned)t) {
                if (--budget <= 0) break;
                __builtin_amdgcn_s_sleep(2);
            }
        }
        __syncthreads();   // bar_A: poll done + x staged

        // ---- phase 2: reload h(t), stage into Bstage ----
        if (t > 0) {
            const u64* hs = h_buf + (size_t)(t & 1) * 16384;
            const u64 a0 = h_ld(hs + ca0), a1 = h_ld(hs + ca0 + 1);
            const u64 b0 = h_ld(hs + ca1), b1 = h_ld(hs + ca1 + 1);
            union { u64 q[2]; short8 v; } u0, u1;
            u0.q[0] = a0; u0.q[1] = a1;
            u1.q[0] = b0; u1.q[1] = b1;
            *(short8*)&Bstage[tid * 8]         = u0.v;
            *(short8*)&Bstage[(tid + 512) * 8] = u1.v;
        } else {
            short8 z = {0, 0, 0, 0, 0, 0, 0, 0};
            *(short8*)&Bstage[tid * 8]         = z;
            *(short8*)&Bstage[(tid + 512) * 8] = z;
        }
        __syncthreads();   // bar_B: Bstage complete

        // ---- MFMA, K=640, two independent accumulator chains ----
        f32x4 acc0 = {0.f, 0.f, 0.f, 0.f}, acc1 = {0.f, 0.f, 0.f, 0.f};
        #pragma unroll
        for (int kk = 0; kk < NKK; kk += 2) {
            const short8 b0 = *(const short8*)&Bstage[(kk * 64 + lane) * 8];
            const short8 b1 = *(const short8*)&Bstage[((kk + 1) * 64 + lane) * 8];
            acc0 = __builtin_amdgcn_mfma_f32_16x16x32_bf16(wfrag[kk], b0, acc0, 0, 0, 0);
            acc1 = __builtin_amdgcn_mfma_f32_16x16x32_bf16(wfrag[kk + 1], b1, acc1, 0, 0, 0);
        }

        // ---- cell: lane-local; h -> LDS block (or hfin at last step) ----
        {
            const float gi = acc0[0] + acc1[0] + bi;
            const float gf = acc0[1] + acc1[1] + bfv;
            const float gg = acc0[2] + acc1[2] + bg;
            const float go = acc0[3] + acc1[3] + bo;
            c_val = fast_sig(gf) * c_val + fast_sig(gi) * fast_tanh(gg);
            const float h = fast_sig(go) * fast_tanh(c_val);
            if (t < T_ - 1) {
                HLDS[col * HS + hu_l] = f2bf(h);
            } else {
                hfin[(size_t)(g * GB + col) * H_ + hu_g] = h;
            }
        }
        __syncthreads();   // bar_C: HLDS complete + Bstage reads done (WAR)

        // ---- wave 0: condensed full-line store of the WG's 1KB h block ----
        if (t < T_ - 1 && w == 0) {
            const u64 d0 = ((const u64*)HLDS)[lane * 2];
            const u64 d1 = ((const u64*)HLDS)[lane * 2 + 1];
            u64* dst = wdst_base + (size_t)((t + 1) & 1) * 16384;
            h_st(dst,     d0);
            h_st(dst + 1, d1);
            asm volatile("s_waitcnt vmcnt(0)" ::: "memory");
            if (lane == 0) f_st(fpub, (unsigned)(t + 1));
        }
        // other waves proceed to next iteration's phase 1 immediately
    }
}

// Head: logits = h_final @ W_out^T, softmax. One wave per batch row.
__global__ void head_kernel(const float* __restrict__ hfin,
                            const float* __restrict__ W_out,
                            float* __restrict__ out)
{
    const int bidx = blockIdx.x;
    const int l    = threadIdx.x;      // 0..63
    float hv[8];
    #pragma unroll
    for (int j = 0; j < 8; ++j) hv[j] = hfin[bidx * 512 + j * 64 + l];
    __shared__ float logits[L_];
    for (int o = 0; o < L_; ++o) {
        float p = 0.f;
        #pragma unroll
        for (int j = 0; j < 8; ++j) p += hv[j] * W_out[o * 512 + j * 64 + l];
        #pragma unroll
        for (int off = 32; off; off >>= 1) p += __shfl_down(p, off, 64);
        if (l == 0) logits[o] = p;
    }
    __syncthreads();
    if (l == 0) {
        float mx = logits[0];
        for (int o = 1; o < L_; ++o) mx = fmaxf(mx, logits[o]);
        float e[L_], sum = 0.f;
        for (int o = 0; o < L_; ++o) { e[o] = __expf(logits[o] - mx); sum += e[o]; }
        const float inv = 1.f / sum;
        for (int o = 0; o < L_; ++o) out[bidx * L_ + o] = e[o] * inv;
    }
}

extern "C" void kernel_launch(void* const* d_in, const int* in_sizes, int n_in,
                              void* d_out, int out_size, void* d_ws, size_t ws_size,
                              hipStream_t stream) {
    const float* x     = (const float*)d_in[0];
    const float* W_ih  = (const float*)d_in[1];
    const float* W_hh  = (const float*)d_in[2];
    const float* bias  = (const float*)d_in[3];
    const float* W_out = (const float*)d_in[4];
    float* out = (float*)d_out;

    // ws: h_buf [2][8][16][128] u64 (262144 B, no memset needed: t=0 is
    //     zero-filled in-kernel) | flags [8][16] u32 (memset, 1024 B pad) |
    //     hfin [128][512] f32 (262144 B)
    char* ws = (char*)d_ws;
    u64*          h_buf = (u64*)ws;
    unsigned int* flags = (unsigned int*)(ws + 262144);
    float*        hfin  = (float*)(ws + 262144 + 1024);

    hipMemsetAsync(flags, 0, 1024, stream);

    void* args[] = { (void*)&x, (void*)&W_ih, (void*)&W_hh, (void*)&bias,
                     (void*)&h_buf, (void*)&flags, (void*)&hfin };
    hipLaunchCooperativeKernel((void*)lstm_kernel, dim3(NG * NS), dim3(512),
                               args, 0, stream);
    head_kernel<<<dim3(B_), dim3(64), 0, stream>>>(hfin, W_out, out);
}